// Round 4
// baseline (2517.671 us; speedup 1.0000x reference)
//
#include <hip/hip_runtime.h>

// Swin window attention, fused per-window kernel, round 4 (= round 3 + bias-index fix).
// Round-3 bug: phase D added cmb at column `li`; the S^T MFMA column maps to the
// global q-row arow = mgrp*16 + li. Fixed to cb[tok*NTOK + arow].
//  - LDS 74 KB => 2 blocks/CU (4 waves/SIMD). Region1 time-shared q -> K -> O.
//  - Swapped QK^T (S^T = mfma(K, q)): per-lane softmax + 2 shfl_xor; P->PV A-frags
//    via register shuffles (no LDS P buffer).
//  - prep pre-sums bias+mask into combined[wi][h][tok][row].

#define NTOK 49
#define DIM 384
#define HEADS 12
#define QKV_ELEMS (1152*384)
#define PROJ_ELEMS (384*384)
#define CMB_ELEMS (64*12*49*49)
#define SCALE 0.17677669529663687f
#define VSTR 390

typedef __attribute__((ext_vector_type(8))) __bf16 bf16x8;
typedef __attribute__((ext_vector_type(4))) float f32x4;

union BF8 { bf16x8 v; unsigned short u[8]; };

__device__ __forceinline__ unsigned short f2bf(float f) {
  union { float f; unsigned u; } x; x.f = f;
  unsigned r = x.u + 0x7fffu + ((x.u >> 16) & 1u);   // RNE
  return (unsigned short)(r >> 16);
}

__device__ __forceinline__ bf16x8 zbf8() {
  BF8 z;
  #pragma unroll
  for (int j = 0; j < 8; ++j) z.u[j] = 0;
  return z.v;
}

__global__ void prep_kernel(const float* __restrict__ qkv_w,
                            const float* __restrict__ proj_w,
                            const float* __restrict__ bias_table,
                            const int* __restrict__ rel_idx,
                            const float* __restrict__ mask,
                            unsigned short* __restrict__ wq,
                            unsigned short* __restrict__ wp,
                            float* __restrict__ cmb) {
  int i = blockIdx.x * 256 + threadIdx.x;
  if (i < QKV_ELEMS) {
    wq[i] = f2bf(qkv_w[i]);
  } else if (i < QKV_ELEMS + PROJ_ELEMS) {
    int j = i - QKV_ELEMS;
    wp[j] = f2bf(proj_w[j]);
  } else if (i < QKV_ELEMS + PROJ_ELEMS + CMB_ELEMS) {
    int j = i - QKV_ELEMS - PROJ_ELEMS;
    // layout: ((wi*12 + h)*49 + tok)*49 + row
    int row = j % 49;              // query row
    int tok = (j / 49) % 49;       // key token
    int h   = (j / 2401) % 12;
    int wi  = j / (2401 * 12);
    cmb[j] = bias_table[rel_idx[row * 49 + tok] * HEADS + h]
           + mask[(wi * 49 + row) * 49 + tok];
  }
}

// LDS element offsets (u16 units)
#define OFF_R1 0                       // [49][384] swizzled: q -> K -> O
#define OFF_V  (49*384)                // [49][VSTR=390] plain (bank-spread)
#define LDS_ELEMS (OFF_V + 49*VSTR)    // 37926
#define LDS_BYTES (LDS_ELEMS*2)        // 75852 B  -> 2 blocks/CU

// region1: XOR-swizzle elem-col bits 3..5 by row&7 (conflict-free b128 reads)
__device__ __forceinline__ int swzq(int row, int colE) {
  return row * 384 + (colE ^ ((row & 7) << 3));
}

__global__ __launch_bounds__(512, 4) void fused_win_attn(
    const float* __restrict__ x,
    const float* __restrict__ qkv_b, const float* __restrict__ proj_b,
    const unsigned short* __restrict__ wq, const unsigned short* __restrict__ wp,
    const float* __restrict__ cmb, float* __restrict__ out) {
  extern __shared__ unsigned short lds[];
  unsigned short* r1 = lds + OFF_R1;   // q -> K -> O
  unsigned short* vB = lds + OFF_V;    // V [49][VSTR]

  const int tid  = threadIdx.x;
  const int wave = tid >> 6, lane = tid & 63;
  const int g = lane >> 4, li = lane & 15;
  const int win = blockIdx.x, wi = win & 63;
  const int mgrp = wave >> 1, ng = wave & 1;   // 4 M-tiles x 2 N-halves
  const int arow = mgrp * 16 + li;             // this wave's A/q row (lane li)

  // ---- phase 0: A-fragments (one m-tile, fp32 -> bf16) ----
  bf16x8 afr[12];
  if (arow < NTOK) {
    const float* xr = x + ((long)win * NTOK + arow) * DIM + g * 8;
    #pragma unroll
    for (int ks = 0; ks < 12; ++ks) {
      float4 f0 = *(const float4*)(xr + ks * 32);
      float4 f1 = *(const float4*)(xr + ks * 32 + 4);
      BF8 t;
      t.u[0] = f2bf(f0.x); t.u[1] = f2bf(f0.y); t.u[2] = f2bf(f0.z); t.u[3] = f2bf(f0.w);
      t.u[4] = f2bf(f1.x); t.u[5] = f2bf(f1.y); t.u[6] = f2bf(f1.z); t.u[7] = f2bf(f1.w);
      afr[ks] = t.v;
    }
  } else {
    bf16x8 z = zbf8();
    #pragma unroll
    for (int ks = 0; ks < 12; ++ks) afr[ks] = z;
  }

  // chunk GEMM: 64 output cols/wave, acc[4] over 4 n-tiles, B straight from L2
  auto run_chunk = [&](const unsigned short* wbase, int colbase, f32x4 acc[4]) {
    const unsigned short* b0 = wbase + (size_t)(colbase + li) * DIM + g * 8;
    #pragma unroll
    for (int k2 = 0; k2 < 12; ++k2) {
      bf16x8 bb0 = *(const bf16x8*)(b0 + k2 * 32);
      bf16x8 bb1 = *(const bf16x8*)(b0 + 16 * DIM + k2 * 32);
      bf16x8 bb2 = *(const bf16x8*)(b0 + 32 * DIM + k2 * 32);
      bf16x8 bb3 = *(const bf16x8*)(b0 + 48 * DIM + k2 * 32);
      acc[0] = __builtin_amdgcn_mfma_f32_16x16x32_bf16(afr[k2], bb0, acc[0], 0, 0, 0);
      acc[1] = __builtin_amdgcn_mfma_f32_16x16x32_bf16(afr[k2], bb1, acc[1], 0, 0, 0);
      acc[2] = __builtin_amdgcn_mfma_f32_16x16x32_bf16(afr[k2], bb2, acc[2], 0, 0, 0);
      acc[3] = __builtin_amdgcn_mfma_f32_16x16x32_bf16(afr[k2], bb3, acc[3], 0, 0, 0);
    }
  };

  // ---- phase A: q chunks (c=0..2) -> region1 ----
  for (int c = 0; c < 3; ++c) {
    f32x4 acc[4];
    #pragma unroll
    for (int i = 0; i < 4; ++i) acc[i] = (f32x4){0.f, 0.f, 0.f, 0.f};
    run_chunk(wq, c * 128 + ng * 64, acc);
    #pragma unroll
    for (int nt = 0; nt < 4; ++nt) {
      int colg = c * 128 + ng * 64 + nt * 16 + li;   // q col 0..383
      float qb = qkv_b[colg];
      #pragma unroll
      for (int r4 = 0; r4 < 4; ++r4) {
        int row = mgrp * 16 + g * 4 + r4;
        if (row < NTOK) r1[swzq(row, colg)] = f2bf((acc[nt][r4] + qb) * SCALE);
      }
    }
  }
  __syncthreads();

  // ---- phase B: extract this wave's q B-frags (6 heads x own m-tile) ----
  bf16x8 qa[6];
  #pragma unroll
  for (int t = 0; t < 6; ++t) {
    int h = (t >> 1) * 4 + ng * 2 + (t & 1);
    qa[t] = (arow < NTOK) ? *(const bf16x8*)&r1[swzq(arow, h * 32 + g * 8)] : zbf8();
  }
  __syncthreads();

  // ---- phase C: K chunks (c=3..5) -> region1, V chunks (c=6..8) -> vB ----
  for (int c = 3; c < 9; ++c) {
    f32x4 acc[4];
    #pragma unroll
    for (int i = 0; i < 4; ++i) acc[i] = (f32x4){0.f, 0.f, 0.f, 0.f};
    run_chunk(wq, c * 128 + ng * 64, acc);
    const int isK = (c < 6);
    const int cb0 = c * 128 - (isK ? 384 : 768);
    #pragma unroll
    for (int nt = 0; nt < 4; ++nt) {
      int colg = c * 128 + ng * 64 + nt * 16 + li;
      float qb = qkv_b[colg];
      int cc = cb0 + ng * 64 + nt * 16 + li;
      #pragma unroll
      for (int r4 = 0; r4 < 4; ++r4) {
        int row = mgrp * 16 + g * 4 + r4;
        if (row < NTOK) {
          float val = acc[nt][r4] + qb;
          if (isK) r1[swzq(row, cc)] = f2bf(val);
          else     vB[row * VSTR + cc] = f2bf(val);
        }
      }
    }
  }
  __syncthreads();

  // ---- phase D: S^T = mfma(K, q), +combined, softmax, P->pa shuffles ----
  bf16x8 pa[6][2];
  #pragma unroll
  for (int t = 0; t < 6; ++t) {
    const int h = (t >> 1) * 4 + ng * 2 + (t & 1);
    f32x4 sv[4];
    #pragma unroll
    for (int nt = 0; nt < 4; ++nt) {
      int tok = nt * 16 + li;
      bf16x8 kf = (tok < NTOK) ? *(const bf16x8*)&r1[swzq(tok, h * 32 + g * 8)] : zbf8();
      f32x4 z4 = (f32x4){0.f, 0.f, 0.f, 0.f};
      sv[nt] = __builtin_amdgcn_mfma_f32_16x16x32_bf16(kf, qa[t], z4, 0, 0, 0);
    }
    // add combined bias+mask (layout [tok][qrow]); pad toks -> -1e30
    // S^T output: row = tok = nt*16 + g*4 + r4, col = li -> global qrow = arow
    const float* cb = cmb + (size_t)(wi * HEADS + h) * (NTOK * NTOK);
    #pragma unroll
    for (int nt = 0; nt < 4; ++nt) {
      #pragma unroll
      for (int r4 = 0; r4 < 4; ++r4) {
        int tok = nt * 16 + g * 4 + r4;
        float v;
        if (tok < NTOK) {
          v = sv[nt][r4];
          if (arow < NTOK) v += cb[tok * NTOK + arow];
        } else {
          v = -1e30f;
        }
        sv[nt][r4] = v;
      }
    }
    // softmax over toks for fixed qrow: local 16 + xor 16,32
    float m = -1e30f;
    #pragma unroll
    for (int nt = 0; nt < 4; ++nt)
      #pragma unroll
      for (int r4 = 0; r4 < 4; ++r4) m = fmaxf(m, sv[nt][r4]);
    m = fmaxf(m, __shfl_xor(m, 16));
    m = fmaxf(m, __shfl_xor(m, 32));
    float s = 0.f;
    #pragma unroll
    for (int nt = 0; nt < 4; ++nt)
      #pragma unroll
      for (int r4 = 0; r4 < 4; ++r4) {
        float e = __expf(sv[nt][r4] - m);
        sv[nt][r4] = e;
        s += e;
      }
    s += __shfl_xor(s, 16);
    s += __shfl_xor(s, 32);
    float inv = 1.f / s;
    #pragma unroll
    for (int nt = 0; nt < 4; ++nt)
      #pragma unroll
      for (int r4 = 0; r4 < 4; ++r4) sv[nt][r4] *= inv;

    // P (S^T layout) -> PV A-frags via register shuffles.
    // target lane (g,li): pa[k2].u[j] = P[qrow=arow][tok=k2*32+g*8+j]
    //   source sv[nt = 2*k2 + (g>>1)][r4 = j&3] from lane ((2g+(j>>2))&3)*16+li
    #pragma unroll
    for (int k2 = 0; k2 < 2; ++k2) {
      BF8 pf;
      #pragma unroll
      for (int j = 0; j < 8; ++j) {
        int srcLane = (((g * 2 + (j >> 2)) & 3) << 4) | li;
        float v0 = __shfl(sv[k2 * 2][j & 3], srcLane);
        float v1 = __shfl(sv[k2 * 2 + 1][j & 3], srcLane);
        pf.u[j] = f2bf((g >= 2) ? v1 : v0);
      }
      pa[t][k2] = pf.v;
    }
  }
  __syncthreads();   // K region dead -> O may overwrite

  // ---- phase E: O = P V; O -> region1 ----
  #pragma unroll
  for (int t = 0; t < 6; ++t) {
    const int h = (t >> 1) * 4 + ng * 2 + (t & 1);
    f32x4 oa[2];
    oa[0] = (f32x4){0.f, 0.f, 0.f, 0.f};
    oa[1] = (f32x4){0.f, 0.f, 0.f, 0.f};
    #pragma unroll
    for (int k2 = 0; k2 < 2; ++k2) {
      #pragma unroll
      for (int nt2 = 0; nt2 < 2; ++nt2) {
        BF8 vb;
        #pragma unroll
        for (int j = 0; j < 8; ++j) {
          int tok = k2 * 32 + g * 8 + j;
          vb.u[j] = (tok < NTOK) ? vB[tok * VSTR + h * 32 + nt2 * 16 + li]
                                 : (unsigned short)0;
        }
        oa[nt2] = __builtin_amdgcn_mfma_f32_16x16x32_bf16(pa[t][k2], vb.v, oa[nt2], 0, 0, 0);
      }
    }
    #pragma unroll
    for (int nt2 = 0; nt2 < 2; ++nt2) {
      int col = h * 32 + nt2 * 16 + li;
      #pragma unroll
      for (int r4 = 0; r4 < 4; ++r4) {
        int row = mgrp * 16 + g * 4 + r4;
        if (row < NTOK) r1[swzq(row, col)] = f2bf(oa[nt2][r4]);
      }
    }
  }
  __syncthreads();

  // ---- phase F: proj GEMM from O (region1) ----
  bf16x8 ofr[12];
  if (arow < NTOK) {
    #pragma unroll
    for (int ks = 0; ks < 12; ++ks)
      ofr[ks] = *(const bf16x8*)&r1[swzq(arow, ks * 32 + g * 8)];
  } else {
    bf16x8 z = zbf8();
    #pragma unroll
    for (int ks = 0; ks < 12; ++ks) ofr[ks] = z;
  }
  for (int pc = 0; pc < 3; ++pc) {
    f32x4 acc[4];
    #pragma unroll
    for (int i = 0; i < 4; ++i) acc[i] = (f32x4){0.f, 0.f, 0.f, 0.f};
    const unsigned short* b0 = wp + (size_t)(pc * 128 + ng * 64 + li) * DIM + g * 8;
    #pragma unroll
    for (int k2 = 0; k2 < 12; ++k2) {
      bf16x8 bb0 = *(const bf16x8*)(b0 + k2 * 32);
      bf16x8 bb1 = *(const bf16x8*)(b0 + 16 * DIM + k2 * 32);
      bf16x8 bb2 = *(const bf16x8*)(b0 + 32 * DIM + k2 * 32);
      bf16x8 bb3 = *(const bf16x8*)(b0 + 48 * DIM + k2 * 32);
      acc[0] = __builtin_amdgcn_mfma_f32_16x16x32_bf16(ofr[k2], bb0, acc[0], 0, 0, 0);
      acc[1] = __builtin_amdgcn_mfma_f32_16x16x32_bf16(ofr[k2], bb1, acc[1], 0, 0, 0);
      acc[2] = __builtin_amdgcn_mfma_f32_16x16x32_bf16(ofr[k2], bb2, acc[2], 0, 0, 0);
      acc[3] = __builtin_amdgcn_mfma_f32_16x16x32_bf16(ofr[k2], bb3, acc[3], 0, 0, 0);
    }
    #pragma unroll
    for (int nt = 0; nt < 4; ++nt) {
      int col = pc * 128 + ng * 64 + nt * 16 + li;
      float pb = proj_b[col];
      #pragma unroll
      for (int r4 = 0; r4 < 4; ++r4) {
        int row = mgrp * 16 + g * 4 + r4;
        if (row < NTOK)
          out[((long)win * NTOK + row) * DIM + col] = acc[nt][r4] + pb;
      }
    }
  }
}

extern "C" void kernel_launch(void* const* d_in, const int* in_sizes, int n_in,
                              void* d_out, int out_size, void* d_ws, size_t ws_size,
                              hipStream_t stream) {
  (void)in_sizes; (void)n_in; (void)out_size; (void)ws_size;
  const float* x          = (const float*)d_in[0];
  const float* mask       = (const float*)d_in[1];
  const float* qkv_w      = (const float*)d_in[2];
  const float* qkv_b      = (const float*)d_in[3];
  const float* proj_w     = (const float*)d_in[4];
  const float* proj_b     = (const float*)d_in[5];
  const float* bias_table = (const float*)d_in[6];
  const int*   rel_idx    = (const int*)d_in[7];
  float* out = (float*)d_out;

  unsigned short* wq = (unsigned short*)d_ws;
  unsigned short* wp = wq + QKV_ELEMS;
  float* cmb = (float*)((char*)d_ws + (size_t)(QKV_ELEMS + PROJ_ELEMS) * 2);

  const int prep_total = QKV_ELEMS + PROJ_ELEMS + CMB_ELEMS;
  prep_kernel<<<(prep_total + 255) / 256, 256, 0, stream>>>(
      qkv_w, proj_w, bias_table, rel_idx, mask, wq, wp, cmb);
  fused_win_attn<<<4096, 512, LDS_BYTES, stream>>>(
      x, qkv_b, proj_b, wq, wp, cmb, out);
}

// Round 5
// 2377.885 us; speedup vs baseline: 1.0588x; 1.0588x over previous
//
#include <hip/hip_runtime.h>

// Swin window attention, fused per-window kernel, round 5.
// Round-4 failure: __launch_bounds__(512,4) + ~160-reg live set -> massive scratch
// spills (WRITE_SIZE 1.09 GB). Fix: per-head-group pipeline so the live set fits.
//  - c-loop over 3 head-groups: GEMM q/K/V chunk(c) -> {r1 stripe, Kbuf, vT};
//    barrier; attention for 4 heads (2 tasks/wave), O overwrites the q stripe
//    in-place (intra-wave read-then-write; rows/cols disjoint across waves);
//    barrier. No qa[6]/pa[6][2] arrays -> per-task live set ~40 regs.
//  - LDS 65 KB (r1 37.6 + Kbuf 12.25 + vT 16) -> 2 blocks/CU.
//  - vT [128][64] XOR-swizzled: PV B-operand is one ds_read_b128 (no scalar gather).

#define NTOK 49
#define DIM 384
#define HEADS 12
#define QKV_ELEMS (1152*384)
#define PROJ_ELEMS (384*384)
#define CMB_ELEMS (64*12*49*49)
#define SCALE 0.17677669529663687f

typedef __attribute__((ext_vector_type(8))) __bf16 bf16x8;
typedef __attribute__((ext_vector_type(4))) float f32x4;

union BF8 { bf16x8 v; unsigned short u[8]; };

__device__ __forceinline__ unsigned short f2bf(float f) {
  union { float f; unsigned u; } x; x.f = f;
  unsigned r = x.u + 0x7fffu + ((x.u >> 16) & 1u);   // RNE
  return (unsigned short)(r >> 16);
}

__device__ __forceinline__ bf16x8 zbf8() {
  BF8 z;
  #pragma unroll
  for (int j = 0; j < 8; ++j) z.u[j] = 0;
  return z.v;
}

__global__ void prep_kernel(const float* __restrict__ qkv_w,
                            const float* __restrict__ proj_w,
                            const float* __restrict__ bias_table,
                            const int* __restrict__ rel_idx,
                            const float* __restrict__ mask,
                            unsigned short* __restrict__ wq,
                            unsigned short* __restrict__ wp,
                            float* __restrict__ cmb) {
  int i = blockIdx.x * 256 + threadIdx.x;
  if (i < QKV_ELEMS) {
    wq[i] = f2bf(qkv_w[i]);
  } else if (i < QKV_ELEMS + PROJ_ELEMS) {
    int j = i - QKV_ELEMS;
    wp[j] = f2bf(proj_w[j]);
  } else if (i < QKV_ELEMS + PROJ_ELEMS + CMB_ELEMS) {
    int j = i - QKV_ELEMS - PROJ_ELEMS;
    // layout: ((wi*12 + h)*49 + tok)*49 + row   (row = query row)
    int row = j % 49;
    int tok = (j / 49) % 49;
    int h   = (j / 2401) % 12;
    int wi  = j / (2401 * 12);
    cmb[j] = bias_table[rel_idx[row * 49 + tok] * HEADS + h]
           + mask[(wi * 49 + row) * 49 + tok];
  }
}

// LDS element offsets (u16 units)
#define OFF_R1 0                        // [49][384] swizzled: q stripes -> O
#define OFF_K  (49*384)                 // 18816: [49][128] swizzled K chunk
#define OFF_VT (OFF_K + 49*128)         // 25088: [128][64] swizzled vT chunk
#define LDS_ELEMS (OFF_VT + 128*64)     // 33280
#define LDS_BYTES (LDS_ELEMS*2)         // 66560 B -> 2 blocks/CU

__device__ __forceinline__ int swzq(int row, int colE) {   // stride 384
  return row * 384 + (colE ^ ((row & 7) << 3));
}
__device__ __forceinline__ int swzk(int row, int colE) {   // stride 128
  return row * 128 + (colE ^ ((row & 7) << 3));
}
__device__ __forceinline__ int swzv(int ch, int tokE) {    // stride 64
  return ch * 64 + (tokE ^ ((ch & 7) << 3));
}

__global__ __launch_bounds__(512, 4) void fused_win_attn(
    const float* __restrict__ x,
    const float* __restrict__ qkv_b, const float* __restrict__ proj_b,
    const unsigned short* __restrict__ wq, const unsigned short* __restrict__ wp,
    const float* __restrict__ cmb, float* __restrict__ out) {
  extern __shared__ unsigned short lds[];
  unsigned short* r1 = lds + OFF_R1;   // q stripes -> O
  unsigned short* kB = lds + OFF_K;    // K chunk [49][128] swizzled
  unsigned short* vT = lds + OFF_VT;   // V chunk transposed [128][64] swizzled

  const int tid  = threadIdx.x;
  const int wave = tid >> 6, lane = tid & 63;
  const int g = lane >> 4, li = lane & 15;
  const int win = blockIdx.x, wi = win & 63;
  const int mgrp = wave >> 1, ng = wave & 1;   // 4 M-tiles x 2 N-halves
  const int arow = mgrp * 16 + li;             // this wave's A/q row (lane li)

  // zero vT (pad tokens must be exact 0 for the PV MFMA); visible after 1st barrier
  {
    uint4 z4 = {0u, 0u, 0u, 0u};
    uint4* p = (uint4*)(lds + OFF_VT);
    p[tid] = z4;
    p[tid + 512] = z4;
  }

  // ---- A-fragments for this wave's m-tile (fp32 -> bf16), persistent ----
  bf16x8 afr[12];
  if (arow < NTOK) {
    const float* xr = x + ((long)win * NTOK + arow) * DIM + g * 8;
    #pragma unroll
    for (int ks = 0; ks < 12; ++ks) {
      float4 f0 = *(const float4*)(xr + ks * 32);
      float4 f1 = *(const float4*)(xr + ks * 32 + 4);
      BF8 t;
      t.u[0] = f2bf(f0.x); t.u[1] = f2bf(f0.y); t.u[2] = f2bf(f0.z); t.u[3] = f2bf(f0.w);
      t.u[4] = f2bf(f1.x); t.u[5] = f2bf(f1.y); t.u[6] = f2bf(f1.z); t.u[7] = f2bf(f1.w);
      afr[ks] = t.v;
    }
  } else {
    bf16x8 z = zbf8();
    #pragma unroll
    for (int ks = 0; ks < 12; ++ks) afr[ks] = z;
  }

  // chunk GEMM: 64 output cols/wave (4 n-tiles), B-frags straight from L2
  auto run_chunk = [&](int colbase, f32x4 acc[4]) {
    const unsigned short* b0 = wq + (size_t)(colbase + li) * DIM + g * 8;
    #pragma unroll
    for (int k2 = 0; k2 < 12; ++k2) {
      bf16x8 bb0 = *(const bf16x8*)(b0 + k2 * 32);
      bf16x8 bb1 = *(const bf16x8*)(b0 + 16 * DIM + k2 * 32);
      bf16x8 bb2 = *(const bf16x8*)(b0 + 32 * DIM + k2 * 32);
      bf16x8 bb3 = *(const bf16x8*)(b0 + 48 * DIM + k2 * 32);
      acc[0] = __builtin_amdgcn_mfma_f32_16x16x32_bf16(afr[k2], bb0, acc[0], 0, 0, 0);
      acc[1] = __builtin_amdgcn_mfma_f32_16x16x32_bf16(afr[k2], bb1, acc[1], 0, 0, 0);
      acc[2] = __builtin_amdgcn_mfma_f32_16x16x32_bf16(afr[k2], bb2, acc[2], 0, 0, 0);
      acc[3] = __builtin_amdgcn_mfma_f32_16x16x32_bf16(afr[k2], bb3, acc[3], 0, 0, 0);
    }
  };

  // ================= head-group pipeline: c = 0..2 =================
  #pragma unroll 1
  for (int c = 0; c < 3; ++c) {
    __syncthreads();   // Kbuf/vT free (prev attention done); iter0: vT zeros done

    // ---- q chunk c -> r1 stripe (scale folded) ----
    {
      f32x4 acc[4];
      #pragma unroll
      for (int i = 0; i < 4; ++i) acc[i] = (f32x4){0.f, 0.f, 0.f, 0.f};
      run_chunk(c * 128 + ng * 64, acc);
      #pragma unroll
      for (int nt = 0; nt < 4; ++nt) {
        int colg = c * 128 + ng * 64 + nt * 16 + li;
        float qb = qkv_b[colg];
        #pragma unroll
        for (int r4 = 0; r4 < 4; ++r4) {
          int row = mgrp * 16 + g * 4 + r4;
          if (row < NTOK) r1[swzq(row, colg)] = f2bf((acc[nt][r4] + qb) * SCALE);
        }
      }
    }
    // ---- K chunk c -> Kbuf ----
    {
      f32x4 acc[4];
      #pragma unroll
      for (int i = 0; i < 4; ++i) acc[i] = (f32x4){0.f, 0.f, 0.f, 0.f};
      run_chunk(384 + c * 128 + ng * 64, acc);
      #pragma unroll
      for (int nt = 0; nt < 4; ++nt) {
        int kcol = ng * 64 + nt * 16 + li;
        float qb = qkv_b[384 + c * 128 + kcol];
        #pragma unroll
        for (int r4 = 0; r4 < 4; ++r4) {
          int row = mgrp * 16 + g * 4 + r4;
          if (row < NTOK) kB[swzk(row, kcol)] = f2bf(acc[nt][r4] + qb);
        }
      }
    }
    // ---- V chunk c -> vT (transposed) ----
    {
      f32x4 acc[4];
      #pragma unroll
      for (int i = 0; i < 4; ++i) acc[i] = (f32x4){0.f, 0.f, 0.f, 0.f};
      run_chunk(768 + c * 128 + ng * 64, acc);
      #pragma unroll
      for (int nt = 0; nt < 4; ++nt) {
        int ch = ng * 64 + nt * 16 + li;
        float qb = qkv_b[768 + c * 128 + ch];
        #pragma unroll
        for (int r4 = 0; r4 < 4; ++r4) {
          int row = mgrp * 16 + g * 4 + r4;
          if (row < NTOK) vT[swzv(ch, row)] = f2bf(acc[nt][r4] + qb);
        }
      }
    }
    __syncthreads();   // q stripe, Kbuf, vT ready

    // ---- attention for the 4 heads of group c; 2 tasks per wave ----
    #pragma unroll 1
    for (int b = 0; b < 2; ++b) {
      const int hh = ng * 2 + b;        // head within chunk (0..3)
      const int h  = c * 4 + hh;        // global head

      bf16x8 qa = (arow < NTOK)
          ? *(const bf16x8*)&r1[swzq(arow, h * 32 + g * 8)] : zbf8();

      // S^T = mfma(K, q): rows = key toks, cols = q rows
      f32x4 sv[4];
      #pragma unroll
      for (int nt = 0; nt < 4; ++nt) {
        int tok = nt * 16 + li;
        bf16x8 kf = (tok < NTOK)
            ? *(const bf16x8*)&kB[swzk(tok, hh * 32 + g * 8)] : zbf8();
        f32x4 z4 = (f32x4){0.f, 0.f, 0.f, 0.f};
        sv[nt] = __builtin_amdgcn_mfma_f32_16x16x32_bf16(kf, qa, z4, 0, 0, 0);
      }

      // + combined bias+mask (layout [tok][qrow]); pad toks -> -1e30
      const float* cb = cmb + (size_t)(wi * HEADS + h) * (NTOK * NTOK);
      #pragma unroll
      for (int nt = 0; nt < 4; ++nt) {
        #pragma unroll
        for (int r4 = 0; r4 < 4; ++r4) {
          int tok = nt * 16 + g * 4 + r4;
          float v;
          if (tok < NTOK) {
            v = sv[nt][r4];
            if (arow < NTOK) v += cb[tok * NTOK + arow];
          } else {
            v = -1e30f;
          }
          sv[nt][r4] = v;
        }
      }

      // softmax over toks for fixed qrow=arow: 16 local + xor 16,32
      float m = -1e30f;
      #pragma unroll
      for (int nt = 0; nt < 4; ++nt)
        #pragma unroll
        for (int r4 = 0; r4 < 4; ++r4) m = fmaxf(m, sv[nt][r4]);
      m = fmaxf(m, __shfl_xor(m, 16));
      m = fmaxf(m, __shfl_xor(m, 32));
      float s = 0.f;
      #pragma unroll
      for (int nt = 0; nt < 4; ++nt)
        #pragma unroll
        for (int r4 = 0; r4 < 4; ++r4) {
          float e = __expf(sv[nt][r4] - m);
          sv[nt][r4] = e;
          s += e;
        }
      s += __shfl_xor(s, 16);
      s += __shfl_xor(s, 32);
      float inv = 1.f / s;
      #pragma unroll
      for (int nt = 0; nt < 4; ++nt)
        #pragma unroll
        for (int r4 = 0; r4 < 4; ++r4) sv[nt][r4] *= inv;

      // P (S^T layout) -> PV A-frags via register shuffles
      // target lane (g,li): pa[k2].u[j] = P[qrow=arow][tok=k2*32+g*8+j]
      //   source sv[nt = 2*k2 + (g>>1)][r4 = j&3] from lane ((2g+(j>>2))&3)*16+li
      bf16x8 pa[2];
      #pragma unroll
      for (int k2 = 0; k2 < 2; ++k2) {
        BF8 pf;
        #pragma unroll
        for (int j = 0; j < 8; ++j) {
          int srcLane = (((g * 2 + (j >> 2)) & 3) << 4) | li;
          float v0 = __shfl(sv[k2 * 2][j & 3], srcLane);
          float v1 = __shfl(sv[k2 * 2 + 1][j & 3], srcLane);
          pf.u[j] = f2bf((g >= 2) ? v1 : v0);
        }
        pa[k2] = pf.v;
      }

      // O = P V (vT b128 reads; pad toks zero)
      f32x4 oa[2];
      oa[0] = (f32x4){0.f, 0.f, 0.f, 0.f};
      oa[1] = (f32x4){0.f, 0.f, 0.f, 0.f};
      #pragma unroll
      for (int k2 = 0; k2 < 2; ++k2) {
        #pragma unroll
        for (int nt2 = 0; nt2 < 2; ++nt2) {
          bf16x8 vb = *(const bf16x8*)&vT[swzv(hh * 32 + nt2 * 16 + li, k2 * 32 + g * 8)];
          oa[nt2] = __builtin_amdgcn_mfma_f32_16x16x32_bf16(pa[k2], vb, oa[nt2], 0, 0, 0);
        }
      }

      // O overwrites this head's q stripe (intra-wave read-then-write; rows
      // disjoint across mgrp waves, cols disjoint across ng/b)
      #pragma unroll
      for (int nt2 = 0; nt2 < 2; ++nt2) {
        int col = h * 32 + nt2 * 16 + li;
        #pragma unroll
        for (int r4 = 0; r4 < 4; ++r4) {
          int row = mgrp * 16 + g * 4 + r4;
          if (row < NTOK) r1[swzq(row, col)] = f2bf(oa[nt2][r4]);
        }
      }
    }
  }
  __syncthreads();

  // ---- proj GEMM from O (r1) ----
  bf16x8 ofr[12];
  if (arow < NTOK) {
    #pragma unroll
    for (int ks = 0; ks < 12; ++ks)
      ofr[ks] = *(const bf16x8*)&r1[swzq(arow, ks * 32 + g * 8)];
  } else {
    bf16x8 z = zbf8();
    #pragma unroll
    for (int ks = 0; ks < 12; ++ks) ofr[ks] = z;
  }
  #pragma unroll 1
  for (int pc = 0; pc < 3; ++pc) {
    f32x4 acc[4];
    #pragma unroll
    for (int i = 0; i < 4; ++i) acc[i] = (f32x4){0.f, 0.f, 0.f, 0.f};
    const unsigned short* b0 = wp + (size_t)(pc * 128 + ng * 64 + li) * DIM + g * 8;
    #pragma unroll
    for (int k2 = 0; k2 < 12; ++k2) {
      bf16x8 bb0 = *(const bf16x8*)(b0 + k2 * 32);
      bf16x8 bb1 = *(const bf16x8*)(b0 + 16 * DIM + k2 * 32);
      bf16x8 bb2 = *(const bf16x8*)(b0 + 32 * DIM + k2 * 32);
      bf16x8 bb3 = *(const bf16x8*)(b0 + 48 * DIM + k2 * 32);
      acc[0] = __builtin_amdgcn_mfma_f32_16x16x32_bf16(ofr[k2], bb0, acc[0], 0, 0, 0);
      acc[1] = __builtin_amdgcn_mfma_f32_16x16x32_bf16(ofr[k2], bb1, acc[1], 0, 0, 0);
      acc[2] = __builtin_amdgcn_mfma_f32_16x16x32_bf16(ofr[k2], bb2, acc[2], 0, 0, 0);
      acc[3] = __builtin_amdgcn_mfma_f32_16x16x32_bf16(ofr[k2], bb3, acc[3], 0, 0, 0);
    }
    #pragma unroll
    for (int nt = 0; nt < 4; ++nt) {
      int col = pc * 128 + ng * 64 + nt * 16 + li;
      float pb = proj_b[col];
      #pragma unroll
      for (int r4 = 0; r4 < 4; ++r4) {
        int row = mgrp * 16 + g * 4 + r4;
        if (row < NTOK)
          out[((long)win * NTOK + row) * DIM + col] = acc[nt][r4] + pb;
      }
    }
  }
}

extern "C" void kernel_launch(void* const* d_in, const int* in_sizes, int n_in,
                              void* d_out, int out_size, void* d_ws, size_t ws_size,
                              hipStream_t stream) {
  (void)in_sizes; (void)n_in; (void)out_size; (void)ws_size;
  const float* x          = (const float*)d_in[0];
  const float* mask       = (const float*)d_in[1];
  const float* qkv_w      = (const float*)d_in[2];
  const float* qkv_b      = (const float*)d_in[3];
  const float* proj_w     = (const float*)d_in[4];
  const float* proj_b     = (const float*)d_in[5];
  const float* bias_table = (const float*)d_in[6];
  const int*   rel_idx    = (const int*)d_in[7];
  float* out = (float*)d_out;

  unsigned short* wq = (unsigned short*)d_ws;
  unsigned short* wp = wq + QKV_ELEMS;
  float* cmb = (float*)((char*)d_ws + (size_t)(QKV_ELEMS + PROJ_ELEMS) * 2);

  const int prep_total = QKV_ELEMS + PROJ_ELEMS + CMB_ELEMS;
  prep_kernel<<<(prep_total + 255) / 256, 256, 0, stream>>>(
      qkv_w, proj_w, bias_table, rel_idx, mask, wq, wp, cmb);
  fused_win_attn<<<4096, 512, LDS_BYTES, stream>>>(
      x, qkv_b, proj_b, wq, wp, cmb, out);
}